// Round 5
// baseline (80.526 us; speedup 1.0000x reference)
//
#include <hip/hip_runtime.h>
#include <math.h>
#include <stdint.h>

// DynamicViewSampler — fused single-kernel bf16 MFMA (K=1, direct output).
// Block = (batch b, 64-col D-slice). 512 threads = 8 waves, 2 waves/SIMD.
// A = m (V=64 x K) packed into fragment order in LDS (plain b128 reads).
// B = v_pad tile staged row-major [l][d] bf16, stride ST2=66 (u16 gather:
//     octet bank offsets {0,8,16,24} + 8 col-dwords -> all 32 banks).
// Cross-tile register prefetch (1-deep), crossing sxy super-tile boundaries.
// out = num/(den+1e-6) written directly; no workspace, no second kernel.

constexpr int VV      = 64;    // views (M)
constexpr int DC      = 64;    // D cols per block (N)
constexpr int KS      = 64;    // L rows per tile (two K=32 MFMA steps)
constexpr int NTH     = 512;
constexpr int ST2     = 66;    // smB row stride in bf16 units
constexpr int SXY_MAX = 512;

typedef __attribute__((ext_vector_type(8))) short short8;
typedef __attribute__((ext_vector_type(4))) float f32x4;

static __device__ __forceinline__ unsigned short f2bf(float f) {
    unsigned u = __builtin_bit_cast(unsigned, f);
    u += 0x7fffu + ((u >> 16) & 1u);          // RNE
    return (unsigned short)(u >> 16);
}

__global__ __launch_bounds__(NTH)
void dvs_fused(const float* __restrict__ v_pad, const int* __restrict__ v_len,
               const int* __restrict__ grid_thws, const float* __restrict__ centers,
               float* __restrict__ out, int B, int L, int D)
{
    const int dcb = blockIdx.x, b = blockIdx.y;
    const int tid  = threadIdx.x;
    const int d0   = dcb * DC;
    const int lane = tid & 63;
    const int wave = tid >> 6;

    __shared__ __align__(16) unsigned short smA[8 * 64 * 8];  // 8 KB
    __shared__ __align__(16) unsigned short smB[KS][ST2];     // ~8.25 KB
    __shared__ float2 sxy[SXY_MAX];                            // 4 KB
    __shared__ float  sden[8][VV];                             // 2 KB
    __shared__ float  sinv[VV];

    // ---- geometry (exact f32 replication of reference) ----
    const int   Lv = v_len[b];
    const float Hf = (float)grid_thws[b*3 + 1];
    const float Wf = (float)grid_thws[b*3 + 2];
    const float sq = sqrtf((float)Lv * (Wf / Hf));
    int W_eff = (int)rintf(sq);                       if (W_eff < 1) W_eff = 1;
    int H_eff = (int)ceilf((float)Lv / (float)W_eff); if (H_eff < 1) H_eff = 1;
    const float invW = 1.f / (float)W_eff, invH = 1.f / (float)H_eff;

    const int l1 = Lv;

    // ---- A-compute role: thread -> view av, k-octet aq (0..7) ----
    const int    av  = tid & 63;
    const int    aq  = tid >> 6;
    const float2 ctr = ((const float2*)centers)[(size_t)b * VV + av];
    const int    amf = av >> 4, ar = av & 15;
    const int    aks = aq >> 2, aoct = aq & 3;
    float denacc = 0.f;

    // ---- B-staging role: rows {brow, brow+32}, float4 col bc4 ----
    const int brow = tid >> 4;   // 0..31
    const int bc4  = tid & 15;

    // ---- fragment / epilogue role ----
    const int fcol = lane & 15, foct = lane >> 4;
    const int nf   = wave & 3;
    const int mfb  = (wave >> 2) * 2;

    f32x4 acc[2];
    acc[0] = f32x4{0.f, 0.f, 0.f, 0.f};
    acc[1] = f32x4{0.f, 0.f, 0.f, 0.f};

    const float* vp_b = v_pad + (size_t)b * L * D + d0;

    // ---- prologue: issue tile-0 loads ----
    float4 ld[2];
#pragma unroll
    for (int p = 0; p < 2; ++p) {
        const int l = p * 32 + brow;
        ld[p] = make_float4(0.f, 0.f, 0.f, 0.f);
        if (l < l1)
            ld[p] = *(const float4*)(vp_b + (size_t)l * D + bc4 * 4);
    }

    for (int st = 0; st < l1; st += SXY_MAX) {
        const int st1 = min(st + SXY_MAX, l1);
        // fill sxy (prev super-tile's readers finished at last tile barrier)
        for (int i = tid; i < st1 - st; i += NTH) {
            const int l   = st + i;
            const int row = l / W_eff;
            const int col = l - row * W_eff;
            sxy[i] = make_float2((float)col * invW, (float)row * invH);
        }
        __syncthreads();                       // sxy visible

        for (int lt = st; lt < st1; lt += KS) {
            // ---- stage B (from regs loaded last iteration / prologue) ----
#pragma unroll
            for (int p = 0; p < 2; ++p) {
                const int lrow = p * 32 + brow;
                unsigned* w = (unsigned*)&smB[lrow][bc4 * 4];
                w[0] = (unsigned)f2bf(ld[p].x) | ((unsigned)f2bf(ld[p].y) << 16);
                w[1] = (unsigned)f2bf(ld[p].z) | ((unsigned)f2bf(ld[p].w) << 16);
            }
            // ---- stage A: m packed into fragment order (1 b128/thread) ----
            {
                union { unsigned short h[8]; short8 s; } ap;
#pragma unroll
                for (int j = 0; j < 8; ++j) {
                    const int kl = aq * 8 + j;
                    const int l  = lt + kl;
                    float m = 0.f;
                    if (l < l1) {
                        const float2 xy = sxy[(lt - st) + kl];
                        const float dx = ctr.x - xy.x, dy = ctr.y - xy.y;
                        m = __expf(-20.f * (dx * dx + dy * dy));
                    }
                    denacc += m;
                    ap.h[j] = f2bf(m);
                }
                ((short8*)smA)[(aks * 4 + amf) * 64 + aoct * 16 + ar] = ap.s;
            }
            __syncthreads();                   // tile staged

            // ---- prefetch next tile (may cross super-tile boundary) ----
            const int ltn = lt + KS;
            if (ltn < l1) {
#pragma unroll
                for (int p = 0; p < 2; ++p) {
                    const int l = ltn + p * 32 + brow;
                    ld[p] = make_float4(0.f, 0.f, 0.f, 0.f);
                    if (l < l1)
                        ld[p] = *(const float4*)(vp_b + (size_t)l * D + bc4 * 4);
                }
            }

            // ---- MFMA: 2 k-halves x 2 m-frags x 1 n-frag per wave ----
#pragma unroll
            for (int ks = 0; ks < 2; ++ks) {
                short8 af[2];
#pragma unroll
                for (int i = 0; i < 2; ++i)
                    af[i] = ((const short8*)smA)[(ks * 4 + mfb + i) * 64 + lane];

                const int kbase = ks * 32 + foct * 8;
                union { unsigned short h[8]; short8 s; } bf;
#pragma unroll
                for (int j = 0; j < 8; ++j)
                    bf.h[j] = smB[kbase + j][nf * 16 + fcol];
#pragma unroll
                for (int i = 0; i < 2; ++i)
                    acc[i] = __builtin_amdgcn_mfma_f32_16x16x32_bf16(
                        af[i], bf.s, acc[i], 0, 0, 0);
            }
            __syncthreads();                   // MFMA reads done; smB reusable
        }
    }

    // ---- denominator reduce (deterministic fixed order) ----
    sden[aq][av] = denacc;
    __syncthreads();
    if (tid < VV) {
        float s = 1e-6f;
#pragma unroll
        for (int r = 0; r < 8; ++r) s += sden[r][tid];
        sinv[tid] = 1.0f / s;
    }
    __syncthreads();

    // ---- epilogue: out = acc * sinv (C/D: col=lane&15, row=(lane>>4)*4+r) ----
    float* outp = out + (size_t)b * VV * D + d0 + nf * 16 + fcol;
#pragma unroll
    for (int i = 0; i < 2; ++i) {
        const int row0 = (mfb + i) * 16 + foct * 4;
#pragma unroll
        for (int r = 0; r < 4; ++r)
            outp[(size_t)(row0 + r) * D] = acc[i][r] * sinv[row0 + r];
    }
}

extern "C" void kernel_launch(void* const* d_in, const int* in_sizes, int n_in,
                              void* d_out, int out_size, void* d_ws, size_t ws_size,
                              hipStream_t stream)
{
    const float* v_pad     = (const float*)d_in[0];
    const int*   v_len     = (const int*)d_in[1];
    const int*   grid_thws = (const int*)d_in[2];
    const float* centers   = (const float*)d_in[3];
    float*       out       = (float*)d_out;

    const int B = in_sizes[1];
    const int D = out_size / (B * VV);
    const int L = in_sizes[0] / (B * D);

    dim3 grid(D / DC, B);
    dvs_fused<<<grid, NTH, 0, stream>>>(v_pad, v_len, grid_thws, centers,
                                        out, B, L, D);
}

// Round 6
// 55.796 us; speedup vs baseline: 1.4432x; 1.4432x over previous
//
#include <hip/hip_runtime.h>
#include <math.h>
#include <stdint.h>

// DynamicViewSampler — bf16 MFMA, fixed 1024-row L-chunks (uniform work items).
// Grid = (L/1024) x (D/64) x B = 1024 blocks, 256 thr (4 waves); blocks whose
// chunk starts past v_len exit immediately -> ~2.5 active blocks/CU, uniform.
// A = m (V=64 x K) packed into fragment order in LDS (plain b128 reads).
// B = v_pad tile staged row-major [l][d] bf16, stride ST2=66 (u16 gather
//     conflict-free: octet banks {0,8,16,24} + 8 col-dwords).
// Cross-tile register prefetch (1-deep). Partials [b][kc][V][D] reduced by
// kernel 2 over the ceil(Lv/1024) valid chunks only (deterministic order).

constexpr int VV      = 64;    // views (M)
constexpr int DC      = 64;    // D cols per block (N)
constexpr int KS      = 64;    // L rows per tile (two K=32 MFMA steps)
constexpr int NTH     = 256;
constexpr int ST2     = 66;    // smB row stride in bf16 units
constexpr int CHUNK   = 1024;  // L rows per block
constexpr int SXY_MAX = 512;

typedef __attribute__((ext_vector_type(8))) short short8;
typedef __attribute__((ext_vector_type(4))) float f32x4;

static __device__ __forceinline__ unsigned short f2bf(float f) {
    unsigned u = __builtin_bit_cast(unsigned, f);
    u += 0x7fffu + ((u >> 16) & 1u);          // RNE
    return (unsigned short)(u >> 16);
}

__global__ __launch_bounds__(NTH)
void dvs_mfma(const float* __restrict__ v_pad, const int* __restrict__ v_len,
              const int* __restrict__ grid_thws, const float* __restrict__ centers,
              float* __restrict__ num_part,   // [B][NKC][V][D]
              float* __restrict__ den_part,   // [B][NKC][V]
              int B, int L, int D, int NKC)
{
    const int kc = blockIdx.x, dcb = blockIdx.y, b = blockIdx.z;
    const int Lv = v_len[b];
    const int l0 = kc * CHUNK;
    if (l0 >= Lv) return;                     // inactive chunk
    const int l1 = min(l0 + CHUNK, Lv);

    const int tid  = threadIdx.x;
    const int d0   = dcb * DC;
    const int lane = tid & 63;
    const int wave = tid >> 6;

    __shared__ __align__(16) unsigned short smA[8 * 64 * 8];  // 8 KB
    __shared__ __align__(16) unsigned short smB[KS][ST2];     // ~8.25 KB
    __shared__ float2 sxy[SXY_MAX];                            // 4 KB
    __shared__ float  sden[4][VV];                             // 1 KB

    // ---- geometry (exact f32 replication of reference) ----
    const float Hf = (float)grid_thws[b*3 + 1];
    const float Wf = (float)grid_thws[b*3 + 2];
    const float sq = sqrtf((float)Lv * (Wf / Hf));
    int W_eff = (int)rintf(sq);                       if (W_eff < 1) W_eff = 1;
    int H_eff = (int)ceilf((float)Lv / (float)W_eff); if (H_eff < 1) H_eff = 1;
    const float invW = 1.f / (float)W_eff, invH = 1.f / (float)H_eff;

    // ---- A-compute role: view av, k-octet aq (0..3), two ks halves ----
    const int    av  = tid & 63;
    const int    aq  = tid >> 6;
    const float2 ctr = ((const float2*)centers)[(size_t)b * VV + av];
    const int    amf = av >> 4, ar = av & 15;
    float denacc = 0.f;

    // ---- B-staging role: 16 float4 cols x 16 row-groups (4 iters) ----
    const int sd   = tid & 15;
    const int srow = tid >> 4;

    // ---- fragment-read role: wave owns n-frag = wave ----
    const int fcol = lane & 15, foct = lane >> 4;

    f32x4 acc[4];
#pragma unroll
    for (int i = 0; i < 4; ++i) acc[i] = f32x4{0.f, 0.f, 0.f, 0.f};

    const float* vp_b = v_pad + (size_t)b * L * D + d0;

    for (int st = l0; st < l1; st += SXY_MAX) {
        const int st1 = min(st + SXY_MAX, l1);
        __syncthreads();                       // prior users of sxy/smB done

        // prologue: issue first tile's loads, fill sxy under their latency
        float4 ld[4];
#pragma unroll
        for (int it = 0; it < 4; ++it) {
            const int l = st + it * 16 + srow;
            ld[it] = make_float4(0.f, 0.f, 0.f, 0.f);
            if (l < st1)
                ld[it] = *(const float4*)(vp_b + (size_t)l * D + sd * 4);
        }
        for (int i = tid; i < st1 - st; i += NTH) {
            const int l   = st + i;
            const int row = l / W_eff;
            const int col = l - row * W_eff;
            sxy[i] = make_float2((float)col * invW, (float)row * invH);
        }
        __syncthreads();                       // sxy visible

        for (int lt = st; lt < st1; lt += KS) {
            // ---- stage B (regs from last iteration / prologue) ----
#pragma unroll
            for (int it = 0; it < 4; ++it) {
                const int lrow = it * 16 + srow;
                unsigned* w = (unsigned*)&smB[lrow][sd * 4];
                w[0] = (unsigned)f2bf(ld[it].x) | ((unsigned)f2bf(ld[it].y) << 16);
                w[1] = (unsigned)f2bf(ld[it].z) | ((unsigned)f2bf(ld[it].w) << 16);
            }
            // ---- stage A: m packed into fragment order ----
#pragma unroll
            for (int ks = 0; ks < 2; ++ks) {
                union { unsigned short h[8]; short8 s; } ap;
#pragma unroll
                for (int j = 0; j < 8; ++j) {
                    const int kl = ks * 32 + aq * 8 + j;
                    const int l  = lt + kl;
                    float m = 0.f;
                    if (l < st1) {
                        const float2 xy = sxy[(lt - st) + kl];
                        const float dx = ctr.x - xy.x, dy = ctr.y - xy.y;
                        m = __expf(-20.f * (dx * dx + dy * dy));
                    }
                    denacc += m;
                    ap.h[j] = f2bf(m);
                }
                ((short8*)smA)[(ks * 4 + amf) * 64 + aq * 16 + ar] = ap.s;
            }
            __syncthreads();                   // tile staged

            // ---- prefetch next tile's globals (fly under MFMA phase) ----
            const int ltn = lt + KS;
            if (ltn < st1) {
#pragma unroll
                for (int it = 0; it < 4; ++it) {
                    const int l = ltn + it * 16 + srow;
                    ld[it] = make_float4(0.f, 0.f, 0.f, 0.f);
                    if (l < st1)
                        ld[it] = *(const float4*)(vp_b + (size_t)l * D + sd * 4);
                }
            }

            // ---- MFMA: 2 k-halves x 4 m-frags x 1 n-frag (= wave) ----
#pragma unroll
            for (int ks = 0; ks < 2; ++ks) {
                short8 af[4];
#pragma unroll
                for (int mf = 0; mf < 4; ++mf)
                    af[mf] = ((const short8*)smA)[(ks * 4 + mf) * 64 + lane];

                const int kbase = ks * 32 + foct * 8;
                union { unsigned short h[8]; short8 s; } bf;
#pragma unroll
                for (int j = 0; j < 8; ++j)
                    bf.h[j] = smB[kbase + j][wave * 16 + fcol];
#pragma unroll
                for (int mf = 0; mf < 4; ++mf)
                    acc[mf] = __builtin_amdgcn_mfma_f32_16x16x32_bf16(
                        af[mf], bf.s, acc[mf], 0, 0, 0);
            }
            __syncthreads();                   // MFMA reads done; smB reusable
        }
    }

    // ---- denominator reduce (deterministic fixed order) ----
    sden[aq][av] = denacc;
    __syncthreads();
    if (dcb == 0 && tid < VV) {
        den_part[((size_t)b * NKC + kc) * VV + tid] =
            sden[0][tid] + sden[1][tid] + sden[2][tid] + sden[3][tid];
    }

    // ---- numerator partials (C/D: col=lane&15, row=(lane>>4)*4+r) ----
    float* basep = num_part + ((size_t)b * NKC + kc) * VV * (size_t)D + d0 + wave * 16;
#pragma unroll
    for (int mf = 0; mf < 4; ++mf) {
        const int row0 = mf * 16 + foct * 4;
#pragma unroll
        for (int r = 0; r < 4; ++r)
            basep[(size_t)(row0 + r) * D + fcol] = acc[mf][r];
    }
}

__global__ __launch_bounds__(256)
void dvs_reduce(const float* __restrict__ num_part,
                const float* __restrict__ den_part,
                const int*   __restrict__ v_len,
                float*       __restrict__ out,
                int B, int D, int NKC, int total4)
{
    const int idx = blockIdx.x * 256 + threadIdx.x;
    if (idx >= total4) return;
    const int dq4 = D / 4;
    const int d4  = idx % dq4;
    const int bv  = idx / dq4;
    const int b   = bv / VV;
    const int v   = bv - b * VV;

    const int nk = (v_len[b] + CHUNK - 1) / CHUNK;   // valid chunk slots only

    float  den = 1e-6f;
    float4 num = make_float4(0.f, 0.f, 0.f, 0.f);
    for (int k = 0; k < nk; ++k) {
        den += den_part[((size_t)b * NKC + k) * VV + v];
        const float4 p = ((const float4*)(num_part +
                          (((size_t)b * NKC + k) * VV + v) * (size_t)D))[d4];
        num.x += p.x; num.y += p.y; num.z += p.z; num.w += p.w;
    }
    const float inv = 1.0f / den;
    ((float4*)out)[(size_t)bv * dq4 + d4] =
        make_float4(num.x * inv, num.y * inv, num.z * inv, num.w * inv);
}

extern "C" void kernel_launch(void* const* d_in, const int* in_sizes, int n_in,
                              void* d_out, int out_size, void* d_ws, size_t ws_size,
                              hipStream_t stream)
{
    const float* v_pad     = (const float*)d_in[0];
    const int*   v_len     = (const int*)d_in[1];
    const int*   grid_thws = (const int*)d_in[2];
    const float* centers   = (const float*)d_in[3];
    float*       out       = (float*)d_out;

    const int B = in_sizes[1];
    const int D = out_size / (B * VV);
    const int L = in_sizes[0] / (B * D);
    const int NKC = (L + CHUNK - 1) / CHUNK;

    float* num_part = (float*)d_ws;
    float* den_part = num_part + (size_t)B * NKC * VV * D;

    dim3 grid1(NKC, D / DC, B);
    dvs_mfma<<<grid1, NTH, 0, stream>>>(v_pad, v_len, grid_thws, centers,
                                        num_part, den_part, B, L, D, NKC);

    const int total4 = B * VV * D / 4;
    dvs_reduce<<<(total4 + 255) / 256, 256, 0, stream>>>(num_part, den_part,
                                                         v_len, out, B, D, NKC,
                                                         total4);
}

// Round 7
// 46.096 us; speedup vs baseline: 1.7469x; 1.2104x over previous
//
#include <hip/hip_runtime.h>
#include <hip/hip_bf16.h>
#include <math.h>
#include <stdint.h>

// DynamicViewSampler — bf16 MFMA, DC=128, fixed 256-row valid-only chunks.
// Grid = NKC(16) x D/128(8) x B(16) = 2048 blocks; blocks with l0 >= v_len
// exit immediately -> ~1090 active UNIFORM blocks (4 tiles each): good
// balance + backfill. Partials touched only for valid chunk slots.
// A = m (V=64 x K) packed into fragment order in LDS (plain b128 reads).
// B = v_pad tile staged row-major [l][d] bf16, stride ST2=134 (u16 gather
//     conflict-free: octet dword-banks {0,24,16,8} + 8 col-dword banks).
// Cross-tile register prefetch (1-deep).

constexpr int VV    = 64;    // views (M)
constexpr int DC    = 128;   // D cols per block (N)
constexpr int KS    = 64;    // L rows per tile (two K=32 MFMA steps)
constexpr int NTH   = 256;
constexpr int ST2   = 134;   // smB row stride in bf16 units
constexpr int CHUNK = 256;   // L rows per block (4 tiles)

typedef __attribute__((ext_vector_type(8))) short short8;
typedef __attribute__((ext_vector_type(4))) float f32x4;

static __device__ __forceinline__ unsigned short f2bf(float f) {
    __hip_bfloat16 h = __float2bfloat16(f);           // RNE, compiler-optimal
    return __builtin_bit_cast(unsigned short, h);
}

__global__ __launch_bounds__(NTH)
void dvs_mfma(const float* __restrict__ v_pad, const int* __restrict__ v_len,
              const int* __restrict__ grid_thws, const float* __restrict__ centers,
              float* __restrict__ num_part,   // [B][NKC][V][D]
              float* __restrict__ den_part,   // [B][NKC][V]
              int B, int L, int D, int NKC)
{
    const int kc = blockIdx.x, dcb = blockIdx.y, b = blockIdx.z;
    const int Lv = v_len[b];
    const int l0 = kc * CHUNK;
    if (l0 >= Lv) return;                     // inactive chunk slot
    const int l1 = min(l0 + CHUNK, Lv);

    const int tid  = threadIdx.x;
    const int d0   = dcb * DC;
    const int lane = tid & 63;
    const int wave = tid >> 6;

    __shared__ __align__(16) unsigned short smA[8 * 64 * 8];  // 8 KB
    __shared__ __align__(16) unsigned short smB[KS][ST2];     // ~16.75 KB
    __shared__ float2 sxy[CHUNK];                              // 2 KB
    __shared__ float  sden[4][VV];                             // 1 KB

    // ---- geometry (exact f32 replication of reference) ----
    const float Hf = (float)grid_thws[b*3 + 1];
    const float Wf = (float)grid_thws[b*3 + 2];
    const float sq = sqrtf((float)Lv * (Wf / Hf));
    int W_eff = (int)rintf(sq);                       if (W_eff < 1) W_eff = 1;
    int H_eff = (int)ceilf((float)Lv / (float)W_eff); if (H_eff < 1) H_eff = 1;
    const float invW = 1.f / (float)W_eff, invH = 1.f / (float)H_eff;

    // ---- A-compute role: view av, k-octet aq ----
    const int    av  = tid & 63;
    const int    aq  = tid >> 6;
    const float2 ctr = ((const float2*)centers)[(size_t)b * VV + av];
    const int    amf = av >> 4, ar = av & 15;
    float denacc = 0.f;

    // ---- B-staging role: 32 float4 cols x 8 row-groups ----
    const int sd   = tid & 31;
    const int srow = tid >> 5;

    // ---- fragment-read role ----
    const int fcol = lane & 15, foct = lane >> 4;

    f32x4 acc[4][2];
#pragma unroll
    for (int i = 0; i < 4; ++i) {
        acc[i][0] = f32x4{0.f, 0.f, 0.f, 0.f};
        acc[i][1] = f32x4{0.f, 0.f, 0.f, 0.f};
    }

    const float* vp_b = v_pad + (size_t)b * L * D + d0;

    // ---- prologue: issue tile-0 loads; fill sxy under their latency ----
    float4 ld[8];
#pragma unroll
    for (int it = 0; it < 8; ++it) {
        const int l = l0 + it * 8 + srow;
        ld[it] = make_float4(0.f, 0.f, 0.f, 0.f);
        if (l < l1)
            ld[it] = *(const float4*)(vp_b + (size_t)l * D + sd * 4);
    }
    if (tid < l1 - l0) {
        const int l   = l0 + tid;
        const int row = l / W_eff;
        const int col = l - row * W_eff;
        sxy[tid] = make_float2((float)col * invW, (float)row * invH);
    }
    __syncthreads();                           // sxy visible

    for (int lt = l0; lt < l1; lt += KS) {
        // ---- stage B (regs from last iteration / prologue) ----
#pragma unroll
        for (int it = 0; it < 8; ++it) {
            const int lrow = it * 8 + srow;
            unsigned* w = (unsigned*)&smB[lrow][sd * 4];
            w[0] = (unsigned)f2bf(ld[it].x) | ((unsigned)f2bf(ld[it].y) << 16);
            w[1] = (unsigned)f2bf(ld[it].z) | ((unsigned)f2bf(ld[it].w) << 16);
        }
        // ---- stage A: m packed into fragment order ----
#pragma unroll
        for (int ks = 0; ks < 2; ++ks) {
            union { unsigned short h[8]; short8 s; } ap;
#pragma unroll
            for (int j = 0; j < 8; ++j) {
                const int kl = ks * 32 + aq * 8 + j;
                const int l  = lt + kl;
                float m = 0.f;
                if (l < l1) {
                    const float2 xy = sxy[(lt - l0) + kl];
                    const float dx = ctr.x - xy.x, dy = ctr.y - xy.y;
                    m = __expf(-20.f * (dx * dx + dy * dy));
                }
                denacc += m;
                ap.h[j] = f2bf(m);
            }
            ((short8*)smA)[(ks * 4 + amf) * 64 + aq * 16 + ar] = ap.s;
        }
        __syncthreads();                       // tile staged

        // ---- prefetch next tile's globals (fly under MFMA phase) ----
        const int ltn = lt + KS;
        if (ltn < l1) {
#pragma unroll
            for (int it = 0; it < 8; ++it) {
                const int l = ltn + it * 8 + srow;
                ld[it] = make_float4(0.f, 0.f, 0.f, 0.f);
                if (l < l1)
                    ld[it] = *(const float4*)(vp_b + (size_t)l * D + sd * 4);
            }
        }

        // ---- MFMA: 2 k-halves x 4 m-frags x 2 n-frags ----
#pragma unroll
        for (int ks = 0; ks < 2; ++ks) {
            short8 af[4];
#pragma unroll
            for (int mf = 0; mf < 4; ++mf)
                af[mf] = ((const short8*)smA)[(ks * 4 + mf) * 64 + lane];

#pragma unroll
            for (int nf = 0; nf < 2; ++nf) {
                const int colx  = wave * 32 + nf * 16 + fcol;
                const int kbase = ks * 32 + foct * 8;
                union { unsigned short h[8]; short8 s; } bf;
#pragma unroll
                for (int j = 0; j < 8; ++j)
                    bf.h[j] = smB[kbase + j][colx];
#pragma unroll
                for (int mf = 0; mf < 4; ++mf)
                    acc[mf][nf] = __builtin_amdgcn_mfma_f32_16x16x32_bf16(
                        af[mf], bf.s, acc[mf][nf], 0, 0, 0);
            }
        }
        __syncthreads();                       // MFMA reads done; smB reusable
    }

    // ---- denominator reduce (deterministic fixed order) ----
    sden[aq][av] = denacc;
    __syncthreads();
    if (dcb == 0 && tid < VV) {
        den_part[((size_t)b * NKC + kc) * VV + tid] =
            sden[0][tid] + sden[1][tid] + sden[2][tid] + sden[3][tid];
    }

    // ---- numerator partials (C/D: col=lane&15, row=(lane>>4)*4+r) ----
    float* basep = num_part + ((size_t)b * NKC + kc) * VV * (size_t)D + d0 + wave * 32;
#pragma unroll
    for (int mf = 0; mf < 4; ++mf) {
#pragma unroll
        for (int nf = 0; nf < 2; ++nf) {
            const int colx = nf * 16 + fcol;
            const int row0 = mf * 16 + foct * 4;
#pragma unroll
            for (int r = 0; r < 4; ++r)
                basep[(size_t)(row0 + r) * D + colx] = acc[mf][nf][r];
        }
    }
}

__global__ __launch_bounds__(256)
void dvs_reduce(const float* __restrict__ num_part,
                const float* __restrict__ den_part,
                const int*   __restrict__ v_len,
                float*       __restrict__ out,
                int B, int D, int NKC, int total4)
{
    const int idx = blockIdx.x * 256 + threadIdx.x;
    if (idx >= total4) return;
    const int dq4 = D / 4;
    const int d4  = idx % dq4;
    const int bv  = idx / dq4;
    const int b   = bv / VV;
    const int v   = bv - b * VV;

    const int nk = (v_len[b] + CHUNK - 1) / CHUNK;   // valid chunk slots only

    float  den = 1e-6f;
    float4 num = make_float4(0.f, 0.f, 0.f, 0.f);
    for (int k = 0; k < nk; ++k) {
        den += den_part[((size_t)b * NKC + k) * VV + v];
        const float4 p = ((const float4*)(num_part +
                          (((size_t)b * NKC + k) * VV + v) * (size_t)D))[d4];
        num.x += p.x; num.y += p.y; num.z += p.z; num.w += p.w;
    }
    const float inv = 1.0f / den;
    ((float4*)out)[(size_t)bv * dq4 + d4] =
        make_float4(num.x * inv, num.y * inv, num.z * inv, num.w * inv);
}

extern "C" void kernel_launch(void* const* d_in, const int* in_sizes, int n_in,
                              void* d_out, int out_size, void* d_ws, size_t ws_size,
                              hipStream_t stream)
{
    const float* v_pad     = (const float*)d_in[0];
    const int*   v_len     = (const int*)d_in[1];
    const int*   grid_thws = (const int*)d_in[2];
    const float* centers   = (const float*)d_in[3];
    float*       out       = (float*)d_out;

    const int B = in_sizes[1];
    const int D = out_size / (B * VV);
    const int L = in_sizes[0] / (B * D);
    const int NKC = (L + CHUNK - 1) / CHUNK;   // 16 for L=4096

    float* num_part = (float*)d_ws;
    float* den_part = num_part + (size_t)B * NKC * VV * D;

    dim3 grid1(NKC, D / DC, B);
    dvs_mfma<<<grid1, NTH, 0, stream>>>(v_pad, v_len, grid_thws, centers,
                                        num_part, den_part, B, L, D, NKC);

    const int total4 = B * VV * D / 4;
    dvs_reduce<<<(total4 + 255) / 256, 256, 0, stream>>>(num_part, den_part,
                                                         v_len, out, B, D, NKC,
                                                         total4);
}

// Round 8
// 42.772 us; speedup vs baseline: 1.8827x; 1.0777x over previous
//
#include <hip/hip_runtime.h>
#include <hip/hip_bf16.h>
#include <math.h>
#include <stdint.h>

// DynamicViewSampler — 3-kernel: prep (m -> fragment-ordered bf16 + per-tile
// den), GEMM (bf16 MFMA, A direct from ws, B staged LDS), reduce.
// Decomposition = round-4 (best): K=8 per-batch chunks (rounded to 64),
// DC=128, 1024 blocks. Hot loop has NO exp / A-pack / sxy.

constexpr int VV  = 64;    // views (M)
constexpr int DC  = 128;   // D cols per block (N)
constexpr int KS  = 64;    // L rows per tile
constexpr int NTH = 256;
constexpr int ST2 = 134;   // smB row stride in bf16 units (conflict-free gather)
constexpr int KCH = 8;     // chunks per batch

typedef __attribute__((ext_vector_type(8))) short short8;
typedef __attribute__((ext_vector_type(4))) float f32x4;

static __device__ __forceinline__ unsigned short f2bf(float f) {
    __hip_bfloat16 h = __float2bfloat16(f);
    return __builtin_bit_cast(unsigned short, h);
}

// ---------------- prep: m tiles (fragment order) + per-tile den ----------------
__global__ __launch_bounds__(256)
void dvs_prep(const int* __restrict__ v_len, const int* __restrict__ gthw,
              const float* __restrict__ centers,
              unsigned short* __restrict__ mws,     // [B][NT][8][64] short8
              float* __restrict__ den_tile,         // [B][NT][64]
              int NT)
{
    const int t = blockIdx.x, b = blockIdx.y;
    const int Lv = v_len[b];
    const int lt = t * KS;
    if (lt >= Lv) return;

    const float Hf = (float)gthw[b*3 + 1];
    const float Wf = (float)gthw[b*3 + 2];
    const float sq = sqrtf((float)Lv * (Wf / Hf));
    int W_eff = (int)rintf(sq);                       if (W_eff < 1) W_eff = 1;
    int H_eff = (int)ceilf((float)Lv / (float)W_eff); if (H_eff < 1) H_eff = 1;
    const float invW = 1.f / (float)W_eff, invH = 1.f / (float)H_eff;

    const int tid  = threadIdx.x;
    const int lane = tid & 63, wave = tid >> 6;
    const int ar = lane & 15, koct = lane >> 4;

    __shared__ float sden[2][4][VV];

    short8* mtile = (short8*)mws + ((size_t)b * NT + t) * 8 * 64;

#pragma unroll
    for (int i = 0; i < 2; ++i) {
        const int f  = wave * 2 + i;
        const int ks = f >> 2, mf = f & 3;
        const int v  = mf * 16 + ar;
        const float2 ctr = ((const float2*)centers)[(size_t)b * VV + v];

        int l   = lt + ks * 32 + koct * 8;
        int row = l / W_eff;
        int col = l - row * W_eff;
        float y = (float)row * invH;

        union { unsigned short h[8]; short8 s; } ap;
        float ds = 0.f;
#pragma unroll
        for (int j = 0; j < 8; ++j) {
            float m = 0.f;
            if (l + j < Lv) {
                const float x  = (float)col * invW;
                const float dx = ctr.x - x, dy = ctr.y - y;
                m = __expf(-20.f * (dx * dx + dy * dy));
            }
            ds += m;
            ap.h[j] = f2bf(m);
            if (++col == W_eff) { col = 0; ++row; y = (float)row * invH; }
        }
        mtile[f * 64 + lane] = ap.s;
        sden[ks][koct][v] = ds;           // unique (ks,koct,v) per (f,lane)
    }
    __syncthreads();
    if (tid < VV) {
        float s = 0.f;
#pragma unroll
        for (int ks = 0; ks < 2; ++ks)
#pragma unroll
            for (int q = 0; q < 4; ++q) s += sden[ks][q][tid];
        den_tile[((size_t)b * NT + t) * VV + tid] = s;
    }
}

// ---------------- GEMM: A from ws (global b128), B staged in LDS ----------------
__global__ __launch_bounds__(NTH)
void dvs_mfma(const float* __restrict__ v_pad, const int* __restrict__ v_len,
              const unsigned short* __restrict__ mws,
              const float* __restrict__ den_tile,
              float* __restrict__ num_part,   // [B][KCH][V][D]
              float* __restrict__ den_part,   // [B][KCH][V]
              int L, int D, int NT)
{
    const int kblk = blockIdx.x, dcb = blockIdx.y, b = blockIdx.z;
    const int Lv = v_len[b];
    const int chunk = (((Lv + KCH - 1) / KCH) + 63) & ~63;   // 64-aligned
    const int l0 = kblk * chunk;
    if (l0 >= Lv) return;
    const int l1 = min(l0 + chunk, Lv);

    const int tid  = threadIdx.x;
    const int d0   = dcb * DC;
    const int lane = tid & 63;
    const int wave = tid >> 6;

    __shared__ __align__(16) unsigned short smB[KS][ST2];   // ~16.75 KB

    // B-staging role: 32 float4 cols x 8 row-groups
    const int sd   = tid & 31;
    const int srow = tid >> 5;
    // fragment-read role
    const int fcol = lane & 15, foct = lane >> 4;

    f32x4 acc[4][2];
#pragma unroll
    for (int i = 0; i < 4; ++i) {
        acc[i][0] = f32x4{0.f, 0.f, 0.f, 0.f};
        acc[i][1] = f32x4{0.f, 0.f, 0.f, 0.f};
    }
    float denacc = 0.f;

    const float*  vp_b   = v_pad + (size_t)b * L * D + d0;
    const short8* mws_b  = (const short8*)mws + (size_t)b * NT * 8 * 64;
    const float*  dt_b   = den_tile + (size_t)b * NT * VV;

    // prologue: issue tile-0 B loads
    float4 ld[8];
#pragma unroll
    for (int it = 0; it < 8; ++it) {
        const int l = l0 + it * 8 + srow;
        ld[it] = make_float4(0.f, 0.f, 0.f, 0.f);
        if (l < l1)
            ld[it] = *(const float4*)(vp_b + (size_t)l * D + sd * 4);
    }

    for (int lt = l0; lt < l1; lt += KS) {
        // ---- stage B (regs from last iteration / prologue) ----
#pragma unroll
        for (int it = 0; it < 8; ++it) {
            const int lrow = it * 8 + srow;
            unsigned* w = (unsigned*)&smB[lrow][sd * 4];
            w[0] = (unsigned)f2bf(ld[it].x) | ((unsigned)f2bf(ld[it].y) << 16);
            w[1] = (unsigned)f2bf(ld[it].z) | ((unsigned)f2bf(ld[it].w) << 16);
        }
        __syncthreads();                       // tile staged

        // ---- prefetch next tile's B globals (fly under MFMA phase) ----
        const int ltn = lt + KS;
        if (ltn < l1) {
#pragma unroll
            for (int it = 0; it < 8; ++it) {
                const int l = ltn + it * 8 + srow;
                ld[it] = make_float4(0.f, 0.f, 0.f, 0.f);
                if (l < l1)
                    ld[it] = *(const float4*)(vp_b + (size_t)l * D + sd * 4);
            }
        }

        // ---- A fragments: direct coalesced b128 loads from ws (L2) ----
        const short8* mt = mws_b + ((size_t)(lt >> 6)) * 8 * 64;
        short8 af[2][4];
#pragma unroll
        for (int ks = 0; ks < 2; ++ks)
#pragma unroll
            for (int mf = 0; mf < 4; ++mf)
                af[ks][mf] = mt[(ks * 4 + mf) * 64 + lane];

        // ---- den accumulate (one load per tile, dcb==0 only) ----
        if (dcb == 0 && tid < VV)
            denacc += dt_b[(size_t)(lt >> 6) * VV + tid];

        // ---- MFMA: 2 k-halves x 4 m-frags x 2 n-frags ----
#pragma unroll
        for (int ks = 0; ks < 2; ++ks) {
#pragma unroll
            for (int nf = 0; nf < 2; ++nf) {
                const int colx  = wave * 32 + nf * 16 + fcol;
                const int kbase = ks * 32 + foct * 8;
                union { unsigned short h[8]; short8 s; } bf;
#pragma unroll
                for (int j = 0; j < 8; ++j)
                    bf.h[j] = smB[kbase + j][colx];
#pragma unroll
                for (int mf = 0; mf < 4; ++mf)
                    acc[mf][nf] = __builtin_amdgcn_mfma_f32_16x16x32_bf16(
                        af[ks][mf], bf.s, acc[mf][nf], 0, 0, 0);
            }
        }
        __syncthreads();                       // MFMA reads done; smB reusable
    }

    // ---- den partial ----
    if (dcb == 0 && tid < VV)
        den_part[((size_t)b * KCH + kblk) * VV + tid] = denacc;

    // ---- numerator partials (C/D: col=lane&15, row=(lane>>4)*4+r) ----
    float* basep = num_part + ((size_t)b * KCH + kblk) * VV * (size_t)D + d0 + wave * 32;
#pragma unroll
    for (int mf = 0; mf < 4; ++mf) {
#pragma unroll
        for (int nf = 0; nf < 2; ++nf) {
            const int colx = nf * 16 + fcol;
            const int row0 = mf * 16 + foct * 4;
#pragma unroll
            for (int r = 0; r < 4; ++r)
                basep[(size_t)(row0 + r) * D + colx] = acc[mf][nf][r];
        }
    }
}

// ---------------- reduce ----------------
__global__ __launch_bounds__(256)
void dvs_reduce(const float* __restrict__ num_part,
                const float* __restrict__ den_part,
                const int*   __restrict__ v_len,
                float*       __restrict__ out,
                int D, int total4)
{
    const int idx = blockIdx.x * 256 + threadIdx.x;
    if (idx >= total4) return;
    const int dq4 = D / 4;
    const int d4  = idx % dq4;
    const int bv  = idx / dq4;
    const int b   = bv / VV;
    const int v   = bv - b * VV;

    const int Lv    = v_len[b];
    const int chunk = (((Lv + KCH - 1) / KCH) + 63) & ~63;
    const int nk    = (Lv + chunk - 1) / chunk;      // valid chunk slots

    float  den = 1e-6f;
    float4 num = make_float4(0.f, 0.f, 0.f, 0.f);
    for (int k = 0; k < nk; ++k) {
        den += den_part[((size_t)b * KCH + k) * VV + v];
        const float4 p = ((const float4*)(num_part +
                          (((size_t)b * KCH + k) * VV + v) * (size_t)D))[d4];
        num.x += p.x; num.y += p.y; num.z += p.z; num.w += p.w;
    }
    const float inv = 1.0f / den;
    ((float4*)out)[(size_t)bv * dq4 + d4] =
        make_float4(num.x * inv, num.y * inv, num.z * inv, num.w * inv);
}

extern "C" void kernel_launch(void* const* d_in, const int* in_sizes, int n_in,
                              void* d_out, int out_size, void* d_ws, size_t ws_size,
                              hipStream_t stream)
{
    const float* v_pad     = (const float*)d_in[0];
    const int*   v_len     = (const int*)d_in[1];
    const int*   grid_thws = (const int*)d_in[2];
    const float* centers   = (const float*)d_in[3];
    float*       out       = (float*)d_out;

    const int B  = in_sizes[1];
    const int D  = out_size / (B * VV);
    const int L  = in_sizes[0] / (B * D);
    const int NT = (L + KS - 1) / KS;

    // workspace layout (all 16B-aligned)
    float*          num_part = (float*)d_ws;                               // B*KCH*V*D f32
    float*          den_part = num_part + (size_t)B * KCH * VV * D;        // B*KCH*V
    float*          den_tile = den_part + (size_t)B * KCH * VV;            // B*NT*V
    unsigned short* mws      = (unsigned short*)(den_tile + (size_t)B * NT * VV);

    dim3 gridP(NT, B);
    dvs_prep<<<gridP, 256, 0, stream>>>(v_len, grid_thws, centers, mws,
                                        den_tile, NT);

    dim3 gridG(KCH, D / DC, B);
    dvs_mfma<<<gridG, NTH, 0, stream>>>(v_pad, v_len, mws, den_tile,
                                        num_part, den_part, L, D, NT);

    const int total4 = B * VV * D / 4;
    dvs_reduce<<<(total4 + 255) / 256, 256, 0, stream>>>(num_part, den_part,
                                                         v_len, out, D, total4);
}